// Round 3
// baseline (471.336 us; speedup 1.0000x reference)
//
#include <hip/hip_runtime.h>

typedef _Float16 half2v __attribute__((ext_vector_type(2)));
typedef _Float16 half4 __attribute__((ext_vector_type(4)));
typedef _Float16 half8 __attribute__((ext_vector_type(8)));
typedef float floatx4 __attribute__((ext_vector_type(4)));

#define B_   8
#define SE   4096
#define SD   4096
#define D_   128

#define MT   64     // Q rows per block (4 waves x 16)
#define NT   64     // K rows per tile
#define LDK  136    // Ks row stride in halves (272B, 16B-aligned)
#define LDV  72     // Vts row stride in halves (144B)
#define LDB  136    // kvprep b-tile stride

// ---------- prep 0: W16 = fp16(W), Wlo = fp16(W - W16)  (error split) ----------
__global__ __launch_bounds__(256) void wprep(const float* __restrict__ W,
                                             _Float16* __restrict__ W16,
                                             _Float16* __restrict__ Wlo) {
    int i = blockIdx.x * 256 + threadIdx.x;   // grid 64 -> 16384
    float w = W[i];
    _Float16 hi = (_Float16)w;
    W16[i] = hi;
    Wlo[i] = (_Float16)(w - (float)hi);
}

// ---------- prep 1: k' = fp16(b @ W^T) via error-split MFMA; vT = fp16(b^T) ----------
__global__ __launch_bounds__(256) void kvprep(const float* __restrict__ b,
                                              const _Float16* __restrict__ W16,
                                              const _Float16* __restrict__ Wlo,
                                              _Float16* __restrict__ kp,
                                              _Float16* __restrict__ vT) {
    __shared__ _Float16 bs[64 * LDB];   // fp16 b tile, 17408 B
    const int bb = blockIdx.y;
    const int s0 = blockIdx.x * 64;
    const int tid = threadIdx.x, wave = tid >> 6, lane = tid & 63;
    const int l15 = lane & 15, quad = lane >> 4;

    // stage bs = fp16(b[s0:s0+64][:])
    const float* bg = b + ((size_t)bb * SE + s0) * D_;
    #pragma unroll
    for (int it = 0; it < 4; ++it) {
        int idx = tid + it * 256;          // 0..1023 8-half chunks
        int row = idx >> 4, seg = idx & 15;
        const float* src = bg + row * D_ + seg * 8;
        float4 a = *(const float4*)src;
        float4 c = *(const float4*)(src + 4);
        half8 hv;
        hv[0] = (_Float16)a.x; hv[1] = (_Float16)a.y; hv[2] = (_Float16)a.z; hv[3] = (_Float16)a.w;
        hv[4] = (_Float16)c.x; hv[5] = (_Float16)c.y; hv[6] = (_Float16)c.z; hv[7] = (_Float16)c.w;
        *(half8*)(bs + row * LDB + seg * 8) = hv;
    }
    __syncthreads();

    // k'[s][d] = sum_e b[s][e] W[d][e]  : A = bs rows (m=s), B = W rows (n=d, k=e)
    half8 af[4];
    #pragma unroll
    for (int ks = 0; ks < 4; ++ks)
        af[ks] = *(const half8*)(bs + (wave * 16 + l15) * LDB + ks * 32 + quad * 8);

    floatx4 acc[8];
    #pragma unroll
    for (int nt = 0; nt < 8; ++nt) acc[nt] = (floatx4){0.f, 0.f, 0.f, 0.f};
    #pragma unroll
    for (int ks = 0; ks < 4; ++ks) {
        #pragma unroll
        for (int nt = 0; nt < 8; ++nt) {
            half8 bh = *(const half8*)(W16 + (size_t)(nt * 16 + l15) * 128 + ks * 32 + quad * 8);
            half8 bl = *(const half8*)(Wlo + (size_t)(nt * 16 + l15) * 128 + ks * 32 + quad * 8);
            acc[nt] = __builtin_amdgcn_mfma_f32_16x16x32_f16(af[ks], bh, acc[nt], 0, 0, 0);
            acc[nt] = __builtin_amdgcn_mfma_f32_16x16x32_f16(af[ks], bl, acc[nt], 0, 0, 0);
        }
    }
    // store k' (C: row=s_local=quad*4+r, col=d=nt*16+l15)
    _Float16* kg = kp + ((size_t)bb * SE + s0 + wave * 16) * D_;
    #pragma unroll
    for (int nt = 0; nt < 8; ++nt)
        #pragma unroll
        for (int r = 0; r < 4; ++r)
            kg[(quad * 4 + r) * D_ + nt * 16 + l15] = (_Float16)acc[nt][r];

    // vT = fp16(b^T): thread (d = tid>>1, s-half = tid&1) reads bs column
    {
        const int d = tid >> 1, sh = tid & 1;
        _Float16* vg = vT + ((size_t)bb * D_ + d) * SE + s0 + sh * 32;
        #pragma unroll
        for (int j = 0; j < 16; ++j) {
            int s = sh * 32 + 2 * j;
            half2v w = { bs[s * LDB + d], bs[(s + 1) * LDB + d] };
            *(half2v*)(vg + 2 * j) = w;
        }
    }
}

// ---------- fused flash attention ----------
// S^T = K' Q^T (16x16x32), P register-chained into O += P V (16x16x16).
// Deferred-rescale online softmax: fast path has NO cross-lane ops.
__global__ __launch_bounds__(256) void flash(const float* __restrict__ h,
                                             const _Float16* __restrict__ k,
                                             const _Float16* __restrict__ vT,
                                             float* __restrict__ out) {
    __shared__ _Float16 Ks[NT * LDK];        // 17408 B
    __shared__ _Float16 Vts[D_ * LDV];       // 18432 B -> 35840 B total

    const int bb   = blockIdx.y;
    const int q0   = blockIdx.x * MT;
    const int tid  = threadIdx.x;
    const int wave = tid >> 6;
    const int lane = tid & 63;
    const int l15  = lane & 15;
    const int quad = lane >> 4;

    // Q = fp16(h) as B-operand fragments: B[n=q=l15][k=d=quad*8+j]
    const float* hrow = h + ((size_t)bb * SD + q0 + wave * 16 + l15) * D_;
    half8 qf[4];
    #pragma unroll
    for (int ks = 0; ks < 4; ++ks) {
        float4 a = *(const float4*)(hrow + ks * 32 + quad * 8);
        float4 c = *(const float4*)(hrow + ks * 32 + quad * 8 + 4);
        half8 f;
        f[0] = (_Float16)a.x; f[1] = (_Float16)a.y; f[2] = (_Float16)a.z; f[3] = (_Float16)a.w;
        f[4] = (_Float16)c.x; f[5] = (_Float16)c.y; f[6] = (_Float16)c.z; f[7] = (_Float16)c.w;
        qf[ks] = f;
    }

    floatx4 acc_o[8];
    #pragma unroll
    for (int i = 0; i < 8; ++i) acc_o[i] = (floatx4){0.f, 0.f, 0.f, 0.f};
    float m_q = -1e30f;     // running max for q=l15 (uniform across quads)
    float l_part = 0.f;     // per-lane partial sum for q=l15 (this quad's s only)

    const _Float16* kbase = k + (size_t)bb * SE * D_;
    const _Float16* vbase = vT + (size_t)bb * D_ * SE;

    // staging geometry (fixed per thread)
    const int krow[4] = { (tid + 0) >> 4, (tid + 256) >> 4, (tid + 512) >> 4, (tid + 768) >> 4 };
    const int kseg = tid & 15;
    const int vrow[4] = { (tid + 0) >> 3, (tid + 256) >> 3, (tid + 512) >> 3, (tid + 768) >> 3 };
    const int vseg = tid & 7;

    // preload tile 0 into registers
    uint4 kr[4], vr[4];
    {
        #pragma unroll
        for (int it = 0; it < 4; ++it)
            kr[it] = *(const uint4*)(kbase + krow[it] * D_ + kseg * 8);
        #pragma unroll
        for (int it = 0; it < 4; ++it)
            vr[it] = *(const uint4*)(vbase + (size_t)vrow[it] * SE + vseg * 8);
    }

    for (int t = 0; t < SE / NT; ++t) {
        __syncthreads();   // readers of tile t-1 done; prefetch loads drained
        #pragma unroll
        for (int it = 0; it < 4; ++it)
            *(uint4*)(Ks + krow[it] * LDK + kseg * 8) = kr[it];
        #pragma unroll
        for (int it = 0; it < 4; ++it)
            *(uint4*)(Vts + vrow[it] * LDV + vseg * 8) = vr[it];
        if (t + 1 < SE / NT) {   // issue prefetch for t+1; waits at next barrier
            const _Float16* kg = kbase + (size_t)(t + 1) * NT * D_;
            const _Float16* vg = vbase + (t + 1) * NT;
            #pragma unroll
            for (int it = 0; it < 4; ++it)
                kr[it] = *(const uint4*)(kg + krow[it] * D_ + kseg * 8);
            #pragma unroll
            for (int it = 0; it < 4; ++it)
                vr[it] = *(const uint4*)(vg + (size_t)vrow[it] * SE + vseg * 8);
        }
        __syncthreads();

        // S^T = K Q^T : C row = s_local = quad*4+r, col = q = l15
        floatx4 accs[4];
        #pragma unroll
        for (int st = 0; st < 4; ++st) accs[st] = (floatx4){0.f, 0.f, 0.f, 0.f};
        #pragma unroll
        for (int ks = 0; ks < 4; ++ks) {
            #pragma unroll
            for (int st = 0; st < 4; ++st) {
                half8 af = *(const half8*)(Ks + (st * 16 + l15) * LDK + ks * 32 + quad * 8);
                accs[st] = __builtin_amdgcn_mfma_f32_16x16x32_f16(af, qf[ks], accs[st], 0, 0, 0);
            }
        }

        // deferred-rescale online softmax (fast path: no cross-lane ops)
        float mv16 = accs[0][0];
        #pragma unroll
        for (int st = 0; st < 4; ++st)
            #pragma unroll
            for (int r = 0; r < 4; ++r) mv16 = fmaxf(mv16, accs[st][r]);
        bool cond = mv16 > m_q + 8.f;
        if (__ballot(cond) != 0ull) {        // rare slow path (wave-uniform)
            float mv = mv16;
            mv = fmaxf(mv, __shfl_xor(mv, 16, 64));
            mv = fmaxf(mv, __shfl_xor(mv, 32, 64));   // tile max per q, uniform across quads
            float mnew = fmaxf(m_q, mv);
            float alpha = __expf(m_q - mnew);         // for q = l15
            l_part *= alpha;
            float ab[4];
            #pragma unroll
            for (int r = 0; r < 4; ++r) ab[r] = __shfl(alpha, quad * 4 + r, 64);
            #pragma unroll
            for (int dt = 0; dt < 8; ++dt)
                #pragma unroll
                for (int r = 0; r < 4; ++r) acc_o[dt][r] *= ab[r];
            m_q = mnew;
        }

        // P = exp(S^T - m); pf[st] IS the A-fragment of PV; l accumulated per-lane
        half4 pf[4];
        #pragma unroll
        for (int st = 0; st < 4; ++st)
            #pragma unroll
            for (int r = 0; r < 4; ++r) {
                float p = __expf(accs[st][r] - m_q);
                l_part += p;
                pf[st][r] = (_Float16)p;
            }

        // O += P V : A = pf (regs), B = Vts fragments
        #pragma unroll
        for (int st = 0; st < 4; ++st) {
            #pragma unroll
            for (int dt = 0; dt < 8; ++dt) {
                half4 vf = *(const half4*)(Vts + (dt * 16 + l15) * LDV + st * 16 + quad * 4);
                acc_o[dt] = __builtin_amdgcn_mfma_f32_16x16x16f16(pf[st], vf, acc_o[dt], 0, 0, 0);
            }
        }
    }

    // final l reduction across quads (once), then epilogue
    l_part += __shfl_xor(l_part, 16, 64);
    l_part += __shfl_xor(l_part, 32, 64);
    float linv = 1.f / l_part;               // for q = l15, uniform across quads
    float lb[4];
    #pragma unroll
    for (int r = 0; r < 4; ++r) lb[r] = __shfl(linv, quad * 4 + r, 64);
    float* orow = out + ((size_t)bb * SD + q0 + wave * 16) * D_;
    #pragma unroll
    for (int dt = 0; dt < 8; ++dt)
        #pragma unroll
        for (int r = 0; r < 4; ++r)
            orow[(size_t)(quad * 4 + r) * D_ + dt * 16 + l15] = acc_o[dt][r] * lb[r];
}

extern "C" void kernel_launch(void* const* d_in, const int* in_sizes, int n_in,
                              void* d_out, int out_size, void* d_ws, size_t ws_size,
                              hipStream_t stream) {
    const float* b = (const float*)d_in[0];   // [B, SE, D]
    const float* h = (const float*)d_in[1];   // [B, SD, D]
    const float* W = (const float*)d_in[2];   // [D, D]
    float* out = (float*)d_out;               // [B, SD, D] fp32

    _Float16* W16 = (_Float16*)d_ws;                       // 32 KB
    _Float16* Wlo = W16 + 128 * 128;                       // 32 KB
    _Float16* kp  = Wlo + 128 * 128;                       // [B, SE, D] fp16
    _Float16* vT  = kp + (size_t)B_ * SE * D_;             // [B, D, SE] fp16

    wprep<<<64, 256, 0, stream>>>(W, W16, Wlo);
    kvprep<<<dim3(SE / 64, B_), 256, 0, stream>>>(b, W16, Wlo, kp, vT);
    flash<<<dim3(SD / MT, B_), 256, 0, stream>>>(h, kp, vT, out);
}

// Round 4
// 211.416 us; speedup vs baseline: 2.2294x; 2.2294x over previous
//
#include <hip/hip_runtime.h>

typedef _Float16 half4 __attribute__((ext_vector_type(4)));
typedef _Float16 half8 __attribute__((ext_vector_type(8)));
typedef float floatx4 __attribute__((ext_vector_type(4)));

#define B_   8
#define SE   4096
#define SD   4096
#define D_   128
#define NT   64
#define LDB  136
#define LOG2E 1.44269504f

// async 16B global->LDS: per-lane global address, wave-uniform LDS base (+lane*16 by HW)
__device__ __forceinline__ void cp16_async(const _Float16* g, _Float16* l) {
    __builtin_amdgcn_global_load_lds((const __attribute__((address_space(1))) unsigned int*)g,
                                     (__attribute__((address_space(3))) unsigned int*)l, 16, 0, 0);
}

// ---------- prep 0: W16 = fp16(W), Wlo = fp16(W - W16)  (error split) ----------
__global__ __launch_bounds__(256) void wprep(const float* __restrict__ W,
                                             _Float16* __restrict__ W16,
                                             _Float16* __restrict__ Wlo) {
    int i = blockIdx.x * 256 + threadIdx.x;   // grid 64 -> 16384
    float w = W[i];
    _Float16 hi = (_Float16)w;
    W16[i] = hi;
    Wlo[i] = (_Float16)(w - (float)hi);
}

// ---------- prep 1: k' = fp16(b @ W^T) (error-split MFMA), vT = fp16(b^T) ----------
__global__ __launch_bounds__(256) void kvprep(const float* __restrict__ b,
                                              const _Float16* __restrict__ W16,
                                              const _Float16* __restrict__ Wlo,
                                              _Float16* __restrict__ kp,
                                              _Float16* __restrict__ vT) {
    __shared__ _Float16 bs[64 * LDB];   // 17408 B (reused for k' staging)
    const int bb = blockIdx.y, s0 = blockIdx.x * 64;
    const int tid = threadIdx.x, wave = tid >> 6, lane = tid & 63;
    const int l15 = lane & 15, quad = lane >> 4;

    // phase 1: stage fp16(b tile)
    const float* bg = b + ((size_t)bb * SE + s0) * D_;
    #pragma unroll
    for (int it = 0; it < 4; ++it) {
        int idx = tid + it * 256;
        int row = idx >> 4, seg = idx & 15;
        const float* src = bg + row * D_ + seg * 8;
        float4 a = *(const float4*)src;
        float4 c = *(const float4*)(src + 4);
        half8 hv;
        hv[0] = (_Float16)a.x; hv[1] = (_Float16)a.y; hv[2] = (_Float16)a.z; hv[3] = (_Float16)a.w;
        hv[4] = (_Float16)c.x; hv[5] = (_Float16)c.y; hv[6] = (_Float16)c.z; hv[7] = (_Float16)c.w;
        *(half8*)(bs + row * LDB + seg * 8) = hv;
    }
    __syncthreads();

    // phase 2: k'[s][d] = sum_e b[s][e] W[d][e]
    half8 af[4];
    #pragma unroll
    for (int ks = 0; ks < 4; ++ks)
        af[ks] = *(const half8*)(bs + (wave * 16 + l15) * LDB + ks * 32 + quad * 8);
    floatx4 acc[8];
    #pragma unroll
    for (int nt = 0; nt < 8; ++nt) acc[nt] = (floatx4){0.f, 0.f, 0.f, 0.f};
    #pragma unroll
    for (int ks = 0; ks < 4; ++ks) {
        #pragma unroll
        for (int nt = 0; nt < 8; ++nt) {
            half8 bh = *(const half8*)(W16 + (size_t)(nt * 16 + l15) * 128 + ks * 32 + quad * 8);
            half8 bl = *(const half8*)(Wlo + (size_t)(nt * 16 + l15) * 128 + ks * 32 + quad * 8);
            acc[nt] = __builtin_amdgcn_mfma_f32_16x16x32_f16(af[ks], bh, acc[nt], 0, 0, 0);
            acc[nt] = __builtin_amdgcn_mfma_f32_16x16x32_f16(af[ks], bl, acc[nt], 0, 0, 0);
        }
    }

    // phase 3: vT = fp16(b^T), 8x8 register transpose, half8 coalesced writes
    if (tid < 128) {
        const int sb = tid & 7, dg = tid >> 3;    // s-chunk 0..7, d-group 0..15
        half8 rowv[8];
        #pragma unroll
        for (int j = 0; j < 8; ++j)
            rowv[j] = *(const half8*)(bs + (sb * 8 + j) * LDB + dg * 8);
        #pragma unroll
        for (int r = 0; r < 8; ++r) {
            int d = dg * 8 + r;
            half8 o;
            #pragma unroll
            for (int j = 0; j < 8; ++j) o[j] = rowv[j][r];
            *(half8*)(vT + ((size_t)bb * D_ + d) * SE + s0 + sb * 8) = o;
        }
    }
    __syncthreads();

    // phase 4: k' C-frags -> bs (overwrite), then coalesced row-major writeout
    #pragma unroll
    for (int nt = 0; nt < 8; ++nt)
        #pragma unroll
        for (int r = 0; r < 4; ++r)
            bs[(wave * 16 + quad * 4 + r) * LDB + nt * 16 + l15] = (_Float16)acc[nt][r];
    __syncthreads();
    _Float16* kg = kp + ((size_t)bb * SE + s0) * D_;
    {
        const int row = tid >> 2;
        #pragma unroll
        for (int it = 0; it < 4; ++it) {
            int ch = (tid & 3) + it * 4;          // 16 chunks of 8 halves per row
            half8 v = *(const half8*)(bs + row * LDB + ch * 8);
            *(half8*)(kg + row * D_ + ch * 8) = v;
        }
    }
}

// ---------- fused flash attention ----------
// Double-buffered LDS via global_load_lds (XOR-swizzled chunk images), one
// barrier per tile. S^T = K' Q^T (16x16x32), P register-chained into
// O += P V (16x16x16). Deferred-rescale softmax in base-2 domain.
__global__ __launch_bounds__(256, 2) void flash(const float* __restrict__ h,
                                                const _Float16* __restrict__ k,
                                                const _Float16* __restrict__ vT,
                                                float* __restrict__ out) {
    __shared__ _Float16 KV[2][16384];   // per buf: Ks image 8192 halves + Vts image 8192

    const int bb   = blockIdx.y;
    const int q0   = blockIdx.x * 64;
    const int tid  = threadIdx.x;
    const int wave = tid >> 6;
    const int lane = tid & 63;
    const int l15  = lane & 15;
    const int quad = lane >> 4;

    const _Float16* kbase = k + (size_t)bb * SE * D_;
    const _Float16* vbase = vT + (size_t)bb * D_ * SE;

    // per-lane gather offsets (within-tile, halves); XOR swizzle on the global side
    int koff[4], voff[4];
    #pragma unroll
    for (int j = 0; j < 4; ++j) {
        int i = (wave * 4 + j) * 64 + lane;       // linear 16B chunk index in tile image
        int kr = i >> 4, kpp = i & 15;
        koff[j] = kr * D_ + (kpp ^ (kr & 15)) * 8;
        int vr = i >> 3, vpp = i & 7;
        voff[j] = vr * SE + (vpp ^ (vr & 7)) * 8;
    }

    // issue tile 0 DMA
    {
        _Float16* buf0 = &KV[0][0];
        #pragma unroll
        for (int j = 0; j < 4; ++j) {
            cp16_async(kbase + koff[j], buf0 + (wave * 4 + j) * 512);
            cp16_async(vbase + voff[j], buf0 + 8192 + (wave * 4 + j) * 512);
        }
    }

    // Q = fp16(h * log2e) as B-fragments: B[n=q=l15][k=d=quad*8+j]
    const float* hrow = h + ((size_t)bb * SD + q0 + wave * 16 + l15) * D_;
    half8 qf[4];
    #pragma unroll
    for (int ks = 0; ks < 4; ++ks) {
        float4 a = *(const float4*)(hrow + ks * 32 + quad * 8);
        float4 c = *(const float4*)(hrow + ks * 32 + quad * 8 + 4);
        half8 f;
        f[0] = (_Float16)(a.x * LOG2E); f[1] = (_Float16)(a.y * LOG2E);
        f[2] = (_Float16)(a.z * LOG2E); f[3] = (_Float16)(a.w * LOG2E);
        f[4] = (_Float16)(c.x * LOG2E); f[5] = (_Float16)(c.y * LOG2E);
        f[6] = (_Float16)(c.z * LOG2E); f[7] = (_Float16)(c.w * LOG2E);
        qf[ks] = f;
    }

    floatx4 acc_o[8];
    #pragma unroll
    for (int i = 0; i < 8; ++i) acc_o[i] = (floatx4){0.f, 0.f, 0.f, 0.f};
    float m_q = -1e30f;   // running max (base-2 domain), uniform across quads
    float l_part = 0.f;   // per-lane partial denominator

    for (int t = 0; t < SE / NT; ++t) {
        __syncthreads();   // compiler drains own vmcnt -> tile t landed for all waves
        if (t + 1 < SE / NT) {   // async DMA for t+1; in flight across this tile's compute
            const _Float16* kt = kbase + (size_t)(t + 1) * (NT * D_);
            const _Float16* vt = vbase + (size_t)(t + 1) * NT;
            _Float16* bufn = &KV[(t + 1) & 1][0];
            #pragma unroll
            for (int j = 0; j < 4; ++j) {
                cp16_async(kt + koff[j], bufn + (wave * 4 + j) * 512);
                cp16_async(vt + voff[j], bufn + 8192 + (wave * 4 + j) * 512);
            }
        }
        const _Float16* Kt = KV[t & 1];
        const _Float16* Vt = Kt + 8192;

        // S^T = K Q^T : C row = s_local = quad*4+r, col = q = l15
        floatx4 accs[4];
        #pragma unroll
        for (int st = 0; st < 4; ++st) accs[st] = (floatx4){0.f, 0.f, 0.f, 0.f};
        #pragma unroll
        for (int ks = 0; ks < 4; ++ks) {
            #pragma unroll
            for (int st = 0; st < 4; ++st) {
                half8 af = *(const half8*)(Kt + (st * 16 + l15) * 128 + ((ks * 4 + quad) ^ l15) * 8);
                accs[st] = __builtin_amdgcn_mfma_f32_16x16x32_f16(af, qf[ks], accs[st], 0, 0, 0);
            }
        }

        // deferred-rescale online softmax, base-2 (fast path: no cross-lane ops)
        float mv16 = accs[0][0];
        #pragma unroll
        for (int st = 0; st < 4; ++st)
            #pragma unroll
            for (int r = 0; r < 4; ++r) mv16 = fmaxf(mv16, accs[st][r]);
        bool cond = mv16 > m_q + 11.5f;
        if (__ballot(cond) != 0ull) {        // rare wave-uniform slow path
            float mv = mv16;
            mv = fmaxf(mv, __shfl_xor(mv, 16, 64));
            mv = fmaxf(mv, __shfl_xor(mv, 32, 64));
            float mnew = fmaxf(m_q, mv);
            float alpha = exp2f(m_q - mnew);
            l_part *= alpha;
            float ab[4];
            #pragma unroll
            for (int r = 0; r < 4; ++r) ab[r] = __shfl(alpha, quad * 4 + r, 64);
            #pragma unroll
            for (int dt = 0; dt < 8; ++dt)
                #pragma unroll
                for (int r = 0; r < 4; ++r) acc_o[dt][r] *= ab[r];
            m_q = mnew;
        }

        // P = 2^(S^T - m); pf[st] IS the PV A-fragment
        half4 pf[4];
        #pragma unroll
        for (int st = 0; st < 4; ++st)
            #pragma unroll
            for (int r = 0; r < 4; ++r) {
                float p = exp2f(accs[st][r] - m_q);
                l_part += p;
                pf[st][r] = (_Float16)p;
            }

        // O += P V : B-frag = V^T[d=dt*16+l15][s=st*16+quad*4 ..+3] from swizzled image
        #pragma unroll
        for (int st = 0; st < 4; ++st) {
            #pragma unroll
            for (int dt = 0; dt < 8; ++dt) {
                half4 vf = *(const half4*)(Vt + (dt * 16 + l15) * 64
                                           + (((st * 2 + (quad >> 1)) ^ (l15 & 7)) * 8)
                                           + (quad & 1) * 4);
                acc_o[dt] = __builtin_amdgcn_mfma_f32_16x16x16f16(pf[st], vf, acc_o[dt], 0, 0, 0);
            }
        }
    }

    // final denominator reduction + epilogue
    l_part += __shfl_xor(l_part, 16, 64);
    l_part += __shfl_xor(l_part, 32, 64);
    float linv = 1.f / l_part;
    float lb[4];
    #pragma unroll
    for (int r = 0; r < 4; ++r) lb[r] = __shfl(linv, quad * 4 + r, 64);
    float* orow = out + ((size_t)bb * SD + q0 + wave * 16) * D_;
    #pragma unroll
    for (int dt = 0; dt < 8; ++dt)
        #pragma unroll
        for (int r = 0; r < 4; ++r)
            orow[(size_t)(quad * 4 + r) * D_ + dt * 16 + l15] = acc_o[dt][r] * lb[r];
}

extern "C" void kernel_launch(void* const* d_in, const int* in_sizes, int n_in,
                              void* d_out, int out_size, void* d_ws, size_t ws_size,
                              hipStream_t stream) {
    const float* b = (const float*)d_in[0];   // [B, SE, D]
    const float* h = (const float*)d_in[1];   // [B, SD, D]
    const float* W = (const float*)d_in[2];   // [D, D]
    float* out = (float*)d_out;               // [B, SD, D] fp32

    _Float16* W16 = (_Float16*)d_ws;                       // 32 KB
    _Float16* Wlo = W16 + 128 * 128;                       // 32 KB
    _Float16* kp  = Wlo + 128 * 128;                       // [B, SE, D] fp16
    _Float16* vT  = kp + (size_t)B_ * SE * D_;             // [B, D, SE] fp16

    wprep<<<64, 256, 0, stream>>>(W, W16, Wlo);
    kvprep<<<dim3(SE / 64, B_), 256, 0, stream>>>(b, W16, Wlo, kp, vT);
    flash<<<dim3(SD / 64, B_), 256, 0, stream>>>(h, kp, vT, out);
}